// Round 6
// baseline (1169.567 us; speedup 1.0000x reference)
//
#include <hip/hip_runtime.h>

#define N_NODES 50000
#define NBUCK 782        // ceil(N_NODES / 64)
#define BCAP 2048        // slots per bucket (mean fill 1023, sigma 32)
#define BSHIFT 11

typedef __attribute__((ext_vector_type(8))) short short8;
typedef __attribute__((ext_vector_type(4))) float floatx4;

static __device__ __forceinline__ unsigned short f2bf(float f) {
  unsigned int u = __builtin_bit_cast(unsigned int, f);
  u += 0x7fff + ((u >> 16) & 1);          // RNE
  return (unsigned short)(u >> 16);
}
static __device__ __forceinline__ float bf2f(unsigned short s) {
  unsigned int u = ((unsigned int)s) << 16;
  return __builtin_bit_cast(float, u);
}

// ---------------- input casts ----------------

// x [N][64] f32 -> xbf [N][64] bf16 AND A1[n][64+c] (self half of layer-1 A')
__global__ void cast_x(const float* __restrict__ x, unsigned short* __restrict__ xbf,
                       unsigned short* __restrict__ A1, int total) {
  int i = blockIdx.x * blockDim.x + threadIdx.x;
  if (i >= total) return;
  unsigned short b = f2bf(x[i]);
  xbf[i] = b;
  A1[(size_t)(i >> 6) * 128 + 64 + (i & 63)] = b;
}

__global__ void cast_w(const float* __restrict__ Wl1, const float* __restrict__ Wr1,
                       const float* __restrict__ Wl2, const float* __restrict__ Wr2,
                       unsigned short* __restrict__ W1, unsigned short* __restrict__ W2) {
  int t = blockIdx.x * blockDim.x + threadIdx.x;
  if (t < 128 * 128) {
    int c = t >> 7, k = t & 127;
    W1[t] = f2bf(k < 64 ? Wl1[c * 64 + k] : Wr1[c * 64 + k - 64]);
  } else {
    int t2 = t - 128 * 128;
    if (t2 < 128 * 256) {
      int c = t2 >> 8, k = t2 & 255;
      W2[t2] = f2bf(k < 128 ? Wl2[c * 128 + k] : Wr2[c * 128 + k - 128]);
    }
  }
}

// ---------------- bucketed edge grouping ----------------
// bucket b holds edges with dst in [b*64, b*64+64); fixed 2048-slot regions.
// packed = (src << 6) | (dst & 63)  (src < 2^16 -> fits 22 bits)

__global__ void __launch_bounds__(1024) bucket_scatter(
    const int* __restrict__ src, const int* __restrict__ dst,
    int* __restrict__ bucket_cur, int* __restrict__ buf, int E) {
  __shared__ int hist[NBUCK];
  __shared__ int base_s[NBUCK];
  int t = threadIdx.x;
  for (int i = t; i < NBUCK; i += 1024) hist[i] = 0;
  __syncthreads();
  int e0 = blockIdx.x * 4096;
  int sv[4], dv[4], bv[4];
#pragma unroll
  for (int p = 0; p < 4; ++p) {
    int e = e0 + p * 1024 + t;
    if (e < E) {
      sv[p] = src[e];
      dv[p] = dst[e];
      bv[p] = dv[p] >> 6;
      atomicAdd(&hist[bv[p]], 1);
    } else bv[p] = -1;
  }
  __syncthreads();
  for (int i = t; i < NBUCK; i += 1024) {
    int c = hist[i];
    base_s[i] = c > 0 ? atomicAdd(&bucket_cur[i], c) : 0;
  }
  __syncthreads();
  for (int i = t; i < NBUCK; i += 1024) hist[i] = 0;   // reuse as sub-cursor
  __syncthreads();
#pragma unroll
  for (int p = 0; p < 4; ++p) {
    if (bv[p] >= 0) {
      int sub = base_s[bv[p]] + atomicAdd(&hist[bv[p]], 1);
      if (sub < BCAP) buf[(bv[p] << BSHIFT) + sub] = (sv[p] << 6) | (dv[p] & 63);
    }
  }
}

// ---------------- bucketed LDS-accumulator mean aggregation ----------------

// layer 1: d=64. One block per bucket; LDS accum[64][64] f32 (16 KB).
__global__ void __launch_bounds__(256) agg64_bucket(
    const unsigned short* __restrict__ xbf, const int* __restrict__ bucket_cur,
    const int* __restrict__ buf, unsigned short* __restrict__ A1,
    float* __restrict__ inv_cnt, int n) {
  __shared__ float accum[64 * 64];
  __shared__ int cntS[64];
  const int tid = threadIdx.x;
  const int lane = tid & 63;
  const int wv = tid >> 6;
  const int b = blockIdx.x;
  const int node0 = b << 6;
  for (int i = tid; i < 4096; i += 256) accum[i] = 0.f;
  if (tid < 64) cntS[tid] = 0;
  __syncthreads();
  const int len = min(bucket_cur[b], BCAP);
  const int* ebuf = buf + (b << BSHIFT);
  // histogram (counts)
  for (int i = tid; i < len; i += 256) atomicAdd(&cntS[ebuf[i] & 63], 1);
  // edge adds: 4 edges per wave-iteration, 4 row loads in flight
  const int nquad = len >> 2;
  const int4* ebuf4 = (const int4*)ebuf;
  for (int q = wv; q < nquad; q += 4) {
    int4 p = ebuf4[q];
    float v0 = bf2f(xbf[(size_t)(p.x >> 6) * 64 + lane]);
    float v1 = bf2f(xbf[(size_t)(p.y >> 6) * 64 + lane]);
    float v2 = bf2f(xbf[(size_t)(p.z >> 6) * 64 + lane]);
    float v3 = bf2f(xbf[(size_t)(p.w >> 6) * 64 + lane]);
    atomicAdd(&accum[((p.x & 63) << 6) + lane], v0);
    atomicAdd(&accum[((p.y & 63) << 6) + lane], v1);
    atomicAdd(&accum[((p.z & 63) << 6) + lane], v2);
    atomicAdd(&accum[((p.w & 63) << 6) + lane], v3);
  }
  if (wv == 0) {
    for (int e = len & ~3; e < len; ++e) {
      int p = ebuf[e];
      float v = bf2f(xbf[(size_t)(p >> 6) * 64 + lane]);
      atomicAdd(&accum[((p & 63) << 6) + lane], v);
    }
  }
  __syncthreads();
  if (tid < 64 && node0 + tid < n)
    inv_cnt[node0 + tid] = 1.0f / (float)max(cntS[tid], 1);
  for (int i = tid; i < 4096; i += 256) {
    int d = i >> 6, f = i & 63;
    int nd = node0 + d;
    if (nd < n) {
      float inv = 1.0f / (float)max(cntS[d], 1);
      A1[(size_t)nd * 128 + f] = f2bf(accum[i] * inv);
    }
  }
}

// layer 2: d=128. LDS accum[64][128] f32 (32 KB). Reads self half of A2, writes agg half.
__global__ void __launch_bounds__(256) agg128_bucket(
    const unsigned short* __restrict__ A2c, const int* __restrict__ bucket_cur,
    const int* __restrict__ buf, unsigned short* __restrict__ A2w,
    const float* __restrict__ inv_cnt, int n) {
  __shared__ float accum[64 * 128];
  const int tid = threadIdx.x;
  const int lane = tid & 63;
  const int wv = tid >> 6;
  const int b = blockIdx.x;
  const int node0 = b << 6;
  for (int i = tid; i < 8192; i += 256) accum[i] = 0.f;
  __syncthreads();
  const int len = min(bucket_cur[b], BCAP);
  const int* ebuf = buf + (b << BSHIFT);
  const int nquad = len >> 2;
  const int4* ebuf4 = (const int4*)ebuf;
  for (int q = wv; q < nquad; q += 4) {
    int4 p = ebuf4[q];
    unsigned int u0 = *(const unsigned int*)(A2c + (size_t)(p.x >> 6) * 256 + 128 + lane * 2);
    unsigned int u1 = *(const unsigned int*)(A2c + (size_t)(p.y >> 6) * 256 + 128 + lane * 2);
    unsigned int u2 = *(const unsigned int*)(A2c + (size_t)(p.z >> 6) * 256 + 128 + lane * 2);
    unsigned int u3 = *(const unsigned int*)(A2c + (size_t)(p.w >> 6) * 256 + 128 + lane * 2);
    int a0 = ((p.x & 63) << 7) + lane * 2;
    int a1 = ((p.y & 63) << 7) + lane * 2;
    int a2 = ((p.z & 63) << 7) + lane * 2;
    int a3 = ((p.w & 63) << 7) + lane * 2;
    atomicAdd(&accum[a0], bf2f((unsigned short)u0));
    atomicAdd(&accum[a0 + 1], bf2f((unsigned short)(u0 >> 16)));
    atomicAdd(&accum[a1], bf2f((unsigned short)u1));
    atomicAdd(&accum[a1 + 1], bf2f((unsigned short)(u1 >> 16)));
    atomicAdd(&accum[a2], bf2f((unsigned short)u2));
    atomicAdd(&accum[a2 + 1], bf2f((unsigned short)(u2 >> 16)));
    atomicAdd(&accum[a3], bf2f((unsigned short)u3));
    atomicAdd(&accum[a3 + 1], bf2f((unsigned short)(u3 >> 16)));
  }
  if (wv == 0) {
    for (int e = len & ~3; e < len; ++e) {
      int p = ebuf[e];
      unsigned int u0 = *(const unsigned int*)(A2c + (size_t)(p >> 6) * 256 + 128 + lane * 2);
      int a0 = ((p & 63) << 7) + lane * 2;
      atomicAdd(&accum[a0], bf2f((unsigned short)u0));
      atomicAdd(&accum[a0 + 1], bf2f((unsigned short)(u0 >> 16)));
    }
  }
  __syncthreads();
  // finalize: 4096 bf16-pairs
  for (int i = tid; i < 4096; i += 256) {
    int d = i >> 6, f = (i & 63) * 2;
    int nd = node0 + d;
    if (nd < n) {
      float inv = inv_cnt[nd];
      unsigned int packed = (unsigned int)f2bf(accum[(d << 7) + f] * inv)
                          | ((unsigned int)f2bf(accum[(d << 7) + f + 1] * inv) << 16);
      *(unsigned int*)(A2w + (size_t)nd * 256 + f) = packed;
    }
  }
}

// ---------------- MFMA GEMM: out = relu(A'(n,KP) x W'(128,KP)^T + bias) ----------------

template<int KP, bool BF_OUT>
__global__ void __launch_bounds__(256) mfma_gemm(
    const unsigned short* __restrict__ A, const unsigned short* __restrict__ W,
    const float* __restrict__ bias, unsigned short* __restrict__ outb,
    float* __restrict__ outf, int n, int ostride, int ocol) {
  const int lane = threadIdx.x & 63;
  const int wv = threadIdx.x >> 6;
  const int m = lane & 15;
  const int q = lane >> 4;
  const int r0 = blockIdx.x * 128 + wv * 32;

  floatx4 acc[2][8];
#pragma unroll
  for (int rt = 0; rt < 2; ++rt)
#pragma unroll
    for (int ct = 0; ct < 8; ++ct) acc[rt][ct] = (floatx4){0.f, 0.f, 0.f, 0.f};

  int ra = r0 + m;      if (ra > n - 1) ra = n - 1;
  int rb = r0 + 16 + m; if (rb > n - 1) rb = n - 1;
  const unsigned short* Arow0 = A + (size_t)ra * KP + q * 8;
  const unsigned short* Arow1 = A + (size_t)rb * KP + q * 8;
  const unsigned short* Wrow  = W + (size_t)m * KP + q * 8;

#pragma unroll 1
  for (int kc = 0; kc < KP / 32; ++kc) {
    short8 a0 = *(const short8*)(Arow0 + kc * 32);
    short8 a1 = *(const short8*)(Arow1 + kc * 32);
#pragma unroll
    for (int ct = 0; ct < 8; ++ct) {
      short8 wf = *(const short8*)(Wrow + (size_t)ct * 16 * KP + kc * 32);
      acc[0][ct] = __builtin_amdgcn_mfma_f32_16x16x32_bf16(a0, wf, acc[0][ct], 0, 0, 0);
      acc[1][ct] = __builtin_amdgcn_mfma_f32_16x16x32_bf16(a1, wf, acc[1][ct], 0, 0, 0);
    }
  }

  float bv[8];
#pragma unroll
  for (int ct = 0; ct < 8; ++ct) bv[ct] = bias[ct * 16 + m];

#pragma unroll
  for (int rt = 0; rt < 2; ++rt) {
#pragma unroll
    for (int j = 0; j < 4; ++j) {
      int row = r0 + rt * 16 + q * 4 + j;
      if (row < n) {
#pragma unroll
        for (int ct = 0; ct < 8; ++ct) {
          float v = acc[rt][ct][j] + bv[ct];
          v = v > 0.f ? v : 0.f;
          int col = ct * 16 + m;
          if (BF_OUT) outb[(size_t)row * ostride + ocol + col] = f2bf(v);
          else        outf[(size_t)row * ostride + col] = v;
        }
      }
    }
  }
}

// ---------------- launch ----------------

extern "C" void kernel_launch(void* const* d_in, const int* in_sizes, int n_in,
                              void* d_out, int out_size, void* d_ws, size_t ws_size,
                              hipStream_t stream) {
  const int N = N_NODES;
  const int E = in_sizes[1] / 2;
  const float* x   = (const float*)d_in[0];
  const int*   src = (const int*)d_in[1];
  const int*   dst = src + E;
  const float* Wl1 = (const float*)d_in[2];
  const float* Wr1 = (const float*)d_in[3];
  const float* b1  = (const float*)d_in[4];
  const float* Wl2 = (const float*)d_in[5];
  const float* Wr2 = (const float*)d_in[6];
  const float* b2  = (const float*)d_in[7];
  float* out = (float*)d_out;

  // workspace (~52 MB)
  unsigned short* A1  = (unsigned short*)d_ws;        // N*128 bf16
  unsigned short* A2  = A1 + (size_t)N * 128;         // N*256 bf16
  unsigned short* xbf = A2 + (size_t)N * 256;         // N*64 bf16
  unsigned short* W1  = xbf + (size_t)N * 64;         // 128*128
  unsigned short* W2  = W1 + 128 * 128;               // 128*256
  float* inv_cnt  = (float*)(W2 + 128 * 256);         // N f32
  int* bucket_cur = (int*)(inv_cnt + N);              // NBUCK ints (padded)
  int* buf        = bucket_cur + 784;                 // NBUCK*BCAP ints (16B-aligned)

  hipMemsetAsync(bucket_cur, 0, NBUCK * sizeof(int), stream);
  cast_x<<<(N * 64 + 255) / 256, 256, 0, stream>>>(x, xbf, A1, N * 64);
  cast_w<<<(128 * 128 + 128 * 256 + 255) / 256, 256, 0, stream>>>(Wl1, Wr1, Wl2, Wr2, W1, W2);

  bucket_scatter<<<(E + 4095) / 4096, 1024, 0, stream>>>(src, dst, bucket_cur, buf, E);

  agg64_bucket<<<NBUCK, 256, 0, stream>>>(xbf, bucket_cur, buf, A1, inv_cnt, N);

  int gb = (N + 127) / 128;
  mfma_gemm<128, true><<<gb, 256, 0, stream>>>(A1, W1, b1, A2, nullptr, N, 256, 128);

  agg128_bucket<<<NBUCK, 256, 0, stream>>>(A2, bucket_cur, buf, A2, inv_cnt, N);
  mfma_gemm<256, false><<<gb, 256, 0, stream>>>(A2, W2, b2, nullptr, out, N, 128, 0);
}

// Round 7
// 215.265 us; speedup vs baseline: 5.4332x; 5.4332x over previous
//
#include <hip/hip_runtime.h>

#define N_NODES 50000
#define NBUCK 391        // ceil(N_NODES / 128) -- 128 dst-nodes per bucket
#define BCAP 4096        // slots per bucket (mean fill 2046, sigma ~45)
#define BSHIFT 12

typedef __attribute__((ext_vector_type(8))) short short8;
typedef __attribute__((ext_vector_type(4))) float floatx4;

static __device__ __forceinline__ unsigned short f2bf(float f) {
  unsigned int u = __builtin_bit_cast(unsigned int, f);
  u += 0x7fff + ((u >> 16) & 1);          // RNE
  return (unsigned short)(u >> 16);
}
static __device__ __forceinline__ float bf2f(unsigned short s) {
  unsigned int u = ((unsigned int)s) << 16;
  return __builtin_bit_cast(float, u);
}

// ---------------- input casts ----------------

// x [N][64] f32 -> A1[n][64+c] bf16 (self half of layer-1 A'; also the gather source)
__global__ void cast_x(const float* __restrict__ x, unsigned short* __restrict__ A1, int total) {
  int i = blockIdx.x * blockDim.x + threadIdx.x;
  if (i >= total) return;
  A1[(size_t)(i >> 6) * 128 + 64 + (i & 63)] = f2bf(x[i]);
}

__global__ void cast_w(const float* __restrict__ Wl1, const float* __restrict__ Wr1,
                       const float* __restrict__ Wl2, const float* __restrict__ Wr2,
                       unsigned short* __restrict__ W1, unsigned short* __restrict__ W2) {
  int t = blockIdx.x * blockDim.x + threadIdx.x;
  if (t < 128 * 128) {
    int c = t >> 7, k = t & 127;
    W1[t] = f2bf(k < 64 ? Wl1[c * 64 + k] : Wr1[c * 64 + k - 64]);
  } else {
    int t2 = t - 128 * 128;
    if (t2 < 128 * 256) {
      int c = t2 >> 8, k = t2 & 255;
      W2[t2] = f2bf(k < 128 ? Wl2[c * 128 + k] : Wr2[c * 128 + k - 128]);
    }
  }
}

// ---------------- bucketed edge grouping + per-bucket local CSR ----------------
// bucket b holds edges with dst in [b*128, b*128+128); fixed 4096-slot regions.
// packed = (src << 7) | (dst & 127)  (src < 2^16 -> fits 23 bits)

__global__ void __launch_bounds__(1024) bucket_scatter(
    const int* __restrict__ src, const int* __restrict__ dst,
    int* __restrict__ bucket_cur, int* __restrict__ buf, int E) {
  __shared__ int hist[NBUCK];
  __shared__ int base_s[NBUCK];
  int t = threadIdx.x;
  for (int i = t; i < NBUCK; i += 1024) hist[i] = 0;
  __syncthreads();
  int e0 = blockIdx.x * 4096;
  int sv[4], dv[4], bv[4];
#pragma unroll
  for (int p = 0; p < 4; ++p) {
    int e = e0 + p * 1024 + t;
    if (e < E) {
      sv[p] = src[e];
      dv[p] = dst[e];
      bv[p] = dv[p] >> 7;
      atomicAdd(&hist[bv[p]], 1);
    } else bv[p] = -1;
  }
  __syncthreads();
  for (int i = t; i < NBUCK; i += 1024) {
    int c = hist[i];
    base_s[i] = c > 0 ? atomicAdd(&bucket_cur[i], c) : 0;
  }
  __syncthreads();
  for (int i = t; i < NBUCK; i += 1024) hist[i] = 0;   // reuse as sub-cursor
  __syncthreads();
#pragma unroll
  for (int p = 0; p < 4; ++p) {
    if (bv[p] >= 0) {
      int sub = base_s[bv[p]] + atomicAdd(&hist[bv[p]], 1);
      if (sub < BCAP) buf[(bv[p] << BSHIFT) + sub] = (sv[p] << 7) | (dv[p] & 127);
    }
  }
}

// one block per bucket: stage packed edges in LDS, histogram 128 nodes, prefix scan,
// emit row_start/row_cnt, scatter srcs back IN PLACE (buf becomes src_sorted).
__global__ void __launch_bounds__(256) bucket_csr(
    int* __restrict__ buf, const int* __restrict__ bucket_cur,
    int* __restrict__ row_start, int* __restrict__ row_cnt, int n) {
  __shared__ int eb[BCAP];      // 16 KB staged edges
  __shared__ int cnt[128];
  __shared__ int tmp[128];
  __shared__ int cur[128];
  const int t = threadIdx.x;
  const int b = blockIdx.x;
  const int node0 = b << 7;
  const int len = min(bucket_cur[b], BCAP);
  int* reg = buf + (b << BSHIFT);
  if (t < 128) cnt[t] = 0;
  __syncthreads();
  for (int i = t; i < len; i += 256) {
    int p = reg[i];
    eb[i] = p;
    atomicAdd(&cnt[p & 127], 1);
  }
  __syncthreads();
  if (t < 128) tmp[t] = cnt[t];
  __syncthreads();
#pragma unroll
  for (int off = 1; off < 128; off <<= 1) {
    int u = (t >= off && t < 128) ? tmp[t - off] : 0;
    __syncthreads();
    if (t < 128) tmp[t] += u;
    __syncthreads();
  }
  if (t < 128) {
    int ex = tmp[t] - cnt[t];          // exclusive local prefix
    cur[t] = ex;
    int nd = node0 + t;
    if (nd < n) {
      row_start[nd] = (b << BSHIFT) + ex;
      row_cnt[nd] = cnt[t];
    }
  }
  __syncthreads();
  for (int i = t; i < len; i += 256) {
    int p = eb[i];
    int sub = atomicAdd(&cur[p & 127], 1);
    reg[sub] = p >> 7;                 // in-place: packed -> plain src, grouped by node
  }
}

// ---------------- gather-reduce mean aggregation (wave per node, fp32 acc) ----------------

// layer 1: gathers A1 self half (cols 64..127), writes A1 agg half (cols 0..63)
__global__ void agg_mean64(unsigned short* __restrict__ A1,
    const int* __restrict__ row_start, const int* __restrict__ row_cnt,
    const int* __restrict__ srcs, int n) {
  int wid = (blockIdx.x * blockDim.x + threadIdx.x) >> 6;
  int lane = threadIdx.x & 63;
  if (wid >= n) return;
  int start = row_start[wid];
  int cnt = row_cnt[wid];
  float a0 = 0.f, a1 = 0.f, a2 = 0.f, a3 = 0.f;
  int e = 0;
  for (; e + 4 <= cnt; e += 4) {
    int s0 = srcs[start + e];
    int s1 = srcs[start + e + 1];
    int s2 = srcs[start + e + 2];
    int s3 = srcs[start + e + 3];
    a0 += bf2f(A1[(size_t)s0 * 128 + 64 + lane]);
    a1 += bf2f(A1[(size_t)s1 * 128 + 64 + lane]);
    a2 += bf2f(A1[(size_t)s2 * 128 + 64 + lane]);
    a3 += bf2f(A1[(size_t)s3 * 128 + 64 + lane]);
  }
  for (; e < cnt; ++e) a0 += bf2f(A1[(size_t)srcs[start + e] * 128 + 64 + lane]);
  A1[(size_t)wid * 128 + lane] = f2bf((a0 + a1 + a2 + a3) * (1.0f / (float)max(cnt, 1)));
}

// layer 2: gathers A2 self half (cols 128..255), writes A2 agg half (cols 0..127)
__global__ void agg_mean128(unsigned short* __restrict__ A2,
    const int* __restrict__ row_start, const int* __restrict__ row_cnt,
    const int* __restrict__ srcs, int n) {
  int wid = (blockIdx.x * blockDim.x + threadIdx.x) >> 6;
  int lane = threadIdx.x & 63;
  if (wid >= n) return;
  int start = row_start[wid];
  int cnt = row_cnt[wid];
  float ax = 0.f, ay = 0.f, bx = 0.f, by = 0.f;
  float cx = 0.f, cy = 0.f, dx = 0.f, dy = 0.f;
  int e = 0;
  for (; e + 4 <= cnt; e += 4) {
    int s0 = srcs[start + e];
    int s1 = srcs[start + e + 1];
    int s2 = srcs[start + e + 2];
    int s3 = srcs[start + e + 3];
    unsigned int u0 = *(const unsigned int*)(A2 + (size_t)s0 * 256 + 128 + lane * 2);
    unsigned int u1 = *(const unsigned int*)(A2 + (size_t)s1 * 256 + 128 + lane * 2);
    unsigned int u2 = *(const unsigned int*)(A2 + (size_t)s2 * 256 + 128 + lane * 2);
    unsigned int u3 = *(const unsigned int*)(A2 + (size_t)s3 * 256 + 128 + lane * 2);
    ax += bf2f((unsigned short)u0); ay += bf2f((unsigned short)(u0 >> 16));
    bx += bf2f((unsigned short)u1); by += bf2f((unsigned short)(u1 >> 16));
    cx += bf2f((unsigned short)u2); cy += bf2f((unsigned short)(u2 >> 16));
    dx += bf2f((unsigned short)u3); dy += bf2f((unsigned short)(u3 >> 16));
  }
  for (; e < cnt; ++e) {
    unsigned int u0 = *(const unsigned int*)(A2 + (size_t)srcs[start + e] * 256 + 128 + lane * 2);
    ax += bf2f((unsigned short)u0); ay += bf2f((unsigned short)(u0 >> 16));
  }
  float inv = 1.0f / (float)max(cnt, 1);
  unsigned int packed = (unsigned int)f2bf((ax + bx + cx + dx) * inv)
                      | ((unsigned int)f2bf((ay + by + cy + dy) * inv) << 16);
  *(unsigned int*)(A2 + (size_t)wid * 256 + lane * 2) = packed;
}

// ---------------- MFMA GEMM: out = relu(A'(n,KP) x W'(128,KP)^T + bias) ----------------

template<int KP, bool BF_OUT>
__global__ void __launch_bounds__(256) mfma_gemm(
    const unsigned short* __restrict__ A, const unsigned short* __restrict__ W,
    const float* __restrict__ bias, unsigned short* __restrict__ outb,
    float* __restrict__ outf, int n, int ostride, int ocol) {
  const int lane = threadIdx.x & 63;
  const int wv = threadIdx.x >> 6;
  const int m = lane & 15;
  const int q = lane >> 4;
  const int r0 = blockIdx.x * 128 + wv * 32;

  floatx4 acc[2][8];
#pragma unroll
  for (int rt = 0; rt < 2; ++rt)
#pragma unroll
    for (int ct = 0; ct < 8; ++ct) acc[rt][ct] = (floatx4){0.f, 0.f, 0.f, 0.f};

  int ra = r0 + m;      if (ra > n - 1) ra = n - 1;
  int rb = r0 + 16 + m; if (rb > n - 1) rb = n - 1;
  const unsigned short* Arow0 = A + (size_t)ra * KP + q * 8;
  const unsigned short* Arow1 = A + (size_t)rb * KP + q * 8;
  const unsigned short* Wrow  = W + (size_t)m * KP + q * 8;

#pragma unroll 1
  for (int kc = 0; kc < KP / 32; ++kc) {
    short8 a0 = *(const short8*)(Arow0 + kc * 32);
    short8 a1 = *(const short8*)(Arow1 + kc * 32);
#pragma unroll
    for (int ct = 0; ct < 8; ++ct) {
      short8 wf = *(const short8*)(Wrow + (size_t)ct * 16 * KP + kc * 32);
      acc[0][ct] = __builtin_amdgcn_mfma_f32_16x16x32_bf16(a0, wf, acc[0][ct], 0, 0, 0);
      acc[1][ct] = __builtin_amdgcn_mfma_f32_16x16x32_bf16(a1, wf, acc[1][ct], 0, 0, 0);
    }
  }

  float bv[8];
#pragma unroll
  for (int ct = 0; ct < 8; ++ct) bv[ct] = bias[ct * 16 + m];

#pragma unroll
  for (int rt = 0; rt < 2; ++rt) {
#pragma unroll
    for (int j = 0; j < 4; ++j) {
      int row = r0 + rt * 16 + q * 4 + j;
      if (row < n) {
#pragma unroll
        for (int ct = 0; ct < 8; ++ct) {
          float v = acc[rt][ct][j] + bv[ct];
          v = v > 0.f ? v : 0.f;
          int col = ct * 16 + m;
          if (BF_OUT) outb[(size_t)row * ostride + ocol + col] = f2bf(v);
          else        outf[(size_t)row * ostride + col] = v;
        }
      }
    }
  }
}

// ---------------- launch ----------------

extern "C" void kernel_launch(void* const* d_in, const int* in_sizes, int n_in,
                              void* d_out, int out_size, void* d_ws, size_t ws_size,
                              hipStream_t stream) {
  const int N = N_NODES;
  const int E = in_sizes[1] / 2;
  const float* x   = (const float*)d_in[0];
  const int*   src = (const int*)d_in[1];
  const int*   dst = src + E;
  const float* Wl1 = (const float*)d_in[2];
  const float* Wr1 = (const float*)d_in[3];
  const float* b1  = (const float*)d_in[4];
  const float* Wl2 = (const float*)d_in[5];
  const float* Wr2 = (const float*)d_in[6];
  const float* b2  = (const float*)d_in[7];
  float* out = (float*)d_out;

  // workspace (~45.3 MB)
  unsigned short* A1 = (unsigned short*)d_ws;         // N*128 bf16
  unsigned short* A2 = A1 + (size_t)N * 128;          // N*256 bf16
  unsigned short* W1 = A2 + (size_t)N * 256;          // 128*128
  unsigned short* W2 = W1 + 128 * 128;                // 128*256
  int* row_start  = (int*)(W2 + 128 * 256);           // N
  int* row_cnt    = row_start + N;                    // N
  int* bucket_cur = row_cnt + N;                      // NBUCK (padded to 392)
  int* buf        = bucket_cur + 392;                 // NBUCK*BCAP ints (6.4 MB)

  hipMemsetAsync(bucket_cur, 0, NBUCK * sizeof(int), stream);
  cast_x<<<(N * 64 + 255) / 256, 256, 0, stream>>>(x, A1, N * 64);
  cast_w<<<(128 * 128 + 128 * 256 + 255) / 256, 256, 0, stream>>>(Wl1, Wr1, Wl2, Wr2, W1, W2);

  bucket_scatter<<<(E + 4095) / 4096, 1024, 0, stream>>>(src, dst, bucket_cur, buf, E);
  bucket_csr<<<NBUCK, 256, 0, stream>>>(buf, bucket_cur, row_start, row_cnt, N);

  int ab = (N * 64 + 255) / 256;  // one wave per node
  agg_mean64<<<ab, 256, 0, stream>>>(A1, row_start, row_cnt, buf, N);

  int gb = (N + 127) / 128;
  mfma_gemm<128, true><<<gb, 256, 0, stream>>>(A1, W1, b1, A2, nullptr, N, 256, 128);

  agg_mean128<<<ab, 256, 0, stream>>>(A2, row_start, row_cnt, buf, N);
  mfma_gemm<256, false><<<gb, 256, 0, stream>>>(A2, W2, b2, nullptr, out, N, 128, 0);
}

// Round 9
// 208.078 us; speedup vs baseline: 5.6208x; 1.0345x over previous
//
#include <hip/hip_runtime.h>

#define N_NODES 50000
#define NBUCK 391        // ceil(N_NODES / 128) -- 128 dst-nodes per bucket
#define BCAP 4096        // slots per bucket (mean fill 2046, sigma ~45)
#define BSHIFT 12

typedef __attribute__((ext_vector_type(8))) short short8;
typedef __attribute__((ext_vector_type(4))) float floatx4;

static __device__ __forceinline__ unsigned short f2bf(float f) {
  unsigned int u = __builtin_bit_cast(unsigned int, f);
  u += 0x7fff + ((u >> 16) & 1);          // RNE
  return (unsigned short)(u >> 16);
}
static __device__ __forceinline__ float bf2f(unsigned short s) {
  unsigned int u = ((unsigned int)s) << 16;
  return __builtin_bit_cast(float, u);
}

// ---------------- K1: prep (cast x -> A1 self half, cast weights, zero cursors) ----------------

__global__ void __launch_bounds__(256) prep(
    const float* __restrict__ x,
    const float* __restrict__ Wl1, const float* __restrict__ Wr1,
    const float* __restrict__ Wl2, const float* __restrict__ Wr2,
    unsigned short* __restrict__ A1, unsigned short* __restrict__ W1,
    unsigned short* __restrict__ W2, int* __restrict__ bucket_cur, int n) {
  const int gid = blockIdx.x * 256 + threadIdx.x;
  const int gsz = gridDim.x * 256;
  for (int i = gid; i < n * 64; i += gsz)
    A1[(size_t)(i >> 6) * 128 + 64 + (i & 63)] = f2bf(x[i]);
  for (int i = gid; i < 128 * 128; i += gsz) {
    int c = i >> 7, k = i & 127;
    W1[i] = f2bf(k < 64 ? Wl1[c * 64 + k] : Wr1[c * 64 + k - 64]);
  }
  for (int i = gid; i < 128 * 256; i += gsz) {
    int c = i >> 8, k = i & 255;
    W2[i] = f2bf(k < 128 ? Wl2[c * 128 + k] : Wr2[c * 128 + k - 128]);
  }
  for (int i = gid; i < NBUCK; i += gsz) bucket_cur[i] = 0;
}

// ---------------- K2: bucketed edge scatter ----------------
// bucket b holds edges with dst in [b*128, b*128+128); fixed 4096-slot regions.
// packed = (src << 7) | (dst & 127)

__global__ void __launch_bounds__(1024) bucket_scatter(
    const int* __restrict__ src, const int* __restrict__ dst,
    int* __restrict__ bucket_cur, int* __restrict__ buf, int E) {
  __shared__ int hist[NBUCK];
  __shared__ int base_s[NBUCK];
  int t = threadIdx.x;
  for (int i = t; i < NBUCK; i += 1024) hist[i] = 0;
  __syncthreads();
  int e0 = blockIdx.x * 4096;
  int sv[4], dv[4], bv[4];
#pragma unroll
  for (int p = 0; p < 4; ++p) {
    int e = e0 + p * 1024 + t;
    if (e < E) {
      sv[p] = src[e];
      dv[p] = dst[e];
      bv[p] = dv[p] >> 7;
      atomicAdd(&hist[bv[p]], 1);
    } else bv[p] = -1;
  }
  __syncthreads();
  for (int i = t; i < NBUCK; i += 1024) {
    int c = hist[i];
    base_s[i] = c > 0 ? atomicAdd(&bucket_cur[i], c) : 0;
  }
  __syncthreads();
  for (int i = t; i < NBUCK; i += 1024) hist[i] = 0;   // reuse as sub-cursor
  __syncthreads();
#pragma unroll
  for (int p = 0; p < 4; ++p) {
    if (bv[p] >= 0) {
      int sub = base_s[bv[p]] + atomicAdd(&hist[bv[p]], 1);
      if (sub < BCAP) buf[(bv[p] << BSHIFT) + sub] = (sv[p] << 7) | (dv[p] & 127);
    }
  }
}

// ---------------- K3: per-bucket local CSR + fused layer-1 aggregation ----------------
// One 1024-thread block per bucket: stage packed edges in LDS, histogram+scan 128
// nodes, reorder srcs in place (buf becomes grouped src lists, used again by K5),
// then 16 waves aggregate the bucket's 128 nodes (8 nodes/wave), reading A1 self
// halves (from prep) and writing A1 agg halves.

__global__ void __launch_bounds__(1024) bucket_csr_agg64(
    int* __restrict__ buf, const int* __restrict__ bucket_cur,
    int* __restrict__ row_start, int* __restrict__ row_cnt,
    unsigned short* __restrict__ A1, int n) {
  __shared__ int eb[BCAP];      // 16 KB staged edges
  __shared__ int cnt[128];
  __shared__ int tmp[128];
  __shared__ int cur[128];
  const int t = threadIdx.x;
  const int b = blockIdx.x;
  const int node0 = b << 7;
  const int len = min(bucket_cur[b], BCAP);
  int* reg = buf + (b << BSHIFT);
  if (t < 128) cnt[t] = 0;
  __syncthreads();
  for (int i = t; i < len; i += 1024) {
    int p = reg[i];
    eb[i] = p;
    atomicAdd(&cnt[p & 127], 1);
  }
  __syncthreads();
  if (t < 128) tmp[t] = cnt[t];
  __syncthreads();
#pragma unroll
  for (int off = 1; off < 128; off <<= 1) {
    int u = (t >= off && t < 128) ? tmp[t - off] : 0;
    __syncthreads();
    if (t < 128) tmp[t] += u;
    __syncthreads();
  }
  if (t < 128) {
    int ex = tmp[t] - cnt[t];          // exclusive local prefix
    cur[t] = ex;
    int nd = node0 + t;
    if (nd < n) {
      row_start[nd] = (b << BSHIFT) + ex;
      row_cnt[nd] = cnt[t];
    }
  }
  __syncthreads();
  for (int i = t; i < len; i += 1024) {
    int p = eb[i];
    int sub = atomicAdd(&cur[p & 127], 1);
    reg[sub] = p >> 7;                 // in-place: packed -> plain src, grouped by node
  }
  __syncthreads();                     // drains the global writes (vmcnt) before re-read
  // fused agg64: 16 waves x 8 nodes; reads grouped src lists (L2-hot)
  const int lane = t & 63;
  const int wv = t >> 6;
  for (int loc = wv; loc < 128; loc += 16) {
    int nd = node0 + loc;
    if (nd >= n) break;                // monotonic in loc
    int cn = cnt[loc];
    const int* sp = reg + (tmp[loc] - cn);
    float a0 = 0.f, a1 = 0.f, a2 = 0.f, a3 = 0.f;
    int e = 0;
    for (; e + 4 <= cn; e += 4) {
      int s0 = sp[e];
      int s1 = sp[e + 1];
      int s2 = sp[e + 2];
      int s3 = sp[e + 3];
      a0 += bf2f(A1[(size_t)s0 * 128 + 64 + lane]);
      a1 += bf2f(A1[(size_t)s1 * 128 + 64 + lane]);
      a2 += bf2f(A1[(size_t)s2 * 128 + 64 + lane]);
      a3 += bf2f(A1[(size_t)s3 * 128 + 64 + lane]);
    }
    for (; e < cn; ++e) a0 += bf2f(A1[(size_t)sp[e] * 128 + 64 + lane]);
    A1[(size_t)nd * 128 + lane] = f2bf((a0 + a1 + a2 + a3) * (1.0f / (float)max(cn, 1)));
  }
}

// ---------------- K5: layer-2 aggregation (wave per node) ----------------
// gathers A2 self half (cols 128..255), writes A2 agg half (cols 0..127)

__global__ void agg_mean128(unsigned short* __restrict__ A2,
    const int* __restrict__ row_start, const int* __restrict__ row_cnt,
    const int* __restrict__ srcs, int n) {
  int wid = (blockIdx.x * blockDim.x + threadIdx.x) >> 6;
  int lane = threadIdx.x & 63;
  if (wid >= n) return;
  int start = row_start[wid];
  int cnt = row_cnt[wid];
  float ax = 0.f, ay = 0.f, bx = 0.f, by = 0.f;
  float cx = 0.f, cy = 0.f, dx = 0.f, dy = 0.f;
  int e = 0;
  for (; e + 4 <= cnt; e += 4) {
    int s0 = srcs[start + e];
    int s1 = srcs[start + e + 1];
    int s2 = srcs[start + e + 2];
    int s3 = srcs[start + e + 3];
    unsigned int u0 = *(const unsigned int*)(A2 + (size_t)s0 * 256 + 128 + lane * 2);
    unsigned int u1 = *(const unsigned int*)(A2 + (size_t)s1 * 256 + 128 + lane * 2);
    unsigned int u2 = *(const unsigned int*)(A2 + (size_t)s2 * 256 + 128 + lane * 2);
    unsigned int u3 = *(const unsigned int*)(A2 + (size_t)s3 * 256 + 128 + lane * 2);
    ax += bf2f((unsigned short)u0); ay += bf2f((unsigned short)(u0 >> 16));
    bx += bf2f((unsigned short)u1); by += bf2f((unsigned short)(u1 >> 16));
    cx += bf2f((unsigned short)u2); cy += bf2f((unsigned short)(u2 >> 16));
    dx += bf2f((unsigned short)u3); dy += bf2f((unsigned short)(u3 >> 16));
  }
  for (; e < cnt; ++e) {
    unsigned int u0 = *(const unsigned int*)(A2 + (size_t)srcs[start + e] * 256 + 128 + lane * 2);
    ax += bf2f((unsigned short)u0); ay += bf2f((unsigned short)(u0 >> 16));
  }
  float inv = 1.0f / (float)max(cnt, 1);
  unsigned int packed = (unsigned int)f2bf((ax + bx + cx + dx) * inv)
                      | ((unsigned int)f2bf((ay + by + cy + dy) * inv) << 16);
  *(unsigned int*)(A2 + (size_t)wid * 256 + lane * 2) = packed;
}

// ---------------- K4/K6: MFMA GEMM: out = relu(A'(n,KP) x W'(128,KP)^T + bias) ----------------

template<int KP, bool BF_OUT>
__global__ void __launch_bounds__(256) mfma_gemm(
    const unsigned short* __restrict__ A, const unsigned short* __restrict__ W,
    const float* __restrict__ bias, unsigned short* __restrict__ outb,
    float* __restrict__ outf, int n, int ostride, int ocol) {
  const int lane = threadIdx.x & 63;
  const int wv = threadIdx.x >> 6;
  const int m = lane & 15;
  const int q = lane >> 4;
  const int r0 = blockIdx.x * 128 + wv * 32;

  floatx4 acc[2][8];
#pragma unroll
  for (int rt = 0; rt < 2; ++rt)
#pragma unroll
    for (int ct = 0; ct < 8; ++ct) acc[rt][ct] = (floatx4){0.f, 0.f, 0.f, 0.f};

  int ra = r0 + m;      if (ra > n - 1) ra = n - 1;
  int rb = r0 + 16 + m; if (rb > n - 1) rb = n - 1;
  const unsigned short* Arow0 = A + (size_t)ra * KP + q * 8;
  const unsigned short* Arow1 = A + (size_t)rb * KP + q * 8;
  const unsigned short* Wrow  = W + (size_t)m * KP + q * 8;

#pragma unroll 1
  for (int kc = 0; kc < KP / 32; ++kc) {
    short8 a0 = *(const short8*)(Arow0 + kc * 32);
    short8 a1 = *(const short8*)(Arow1 + kc * 32);
#pragma unroll
    for (int ct = 0; ct < 8; ++ct) {
      short8 wf = *(const short8*)(Wrow + (size_t)ct * 16 * KP + kc * 32);
      acc[0][ct] = __builtin_amdgcn_mfma_f32_16x16x32_bf16(a0, wf, acc[0][ct], 0, 0, 0);
      acc[1][ct] = __builtin_amdgcn_mfma_f32_16x16x32_bf16(a1, wf, acc[1][ct], 0, 0, 0);
    }
  }

  float bv[8];
#pragma unroll
  for (int ct = 0; ct < 8; ++ct) bv[ct] = bias[ct * 16 + m];

#pragma unroll
  for (int rt = 0; rt < 2; ++rt) {
#pragma unroll
    for (int j = 0; j < 4; ++j) {
      int row = r0 + rt * 16 + q * 4 + j;
      if (row < n) {
#pragma unroll
        for (int ct = 0; ct < 8; ++ct) {
          float v = acc[rt][ct][j] + bv[ct];
          v = v > 0.f ? v : 0.f;
          int col = ct * 16 + m;
          if (BF_OUT) outb[(size_t)row * ostride + ocol + col] = f2bf(v);
          else        outf[(size_t)row * ostride + col] = v;
        }
      }
    }
  }
}

// ---------------- launch ----------------

extern "C" void kernel_launch(void* const* d_in, const int* in_sizes, int n_in,
                              void* d_out, int out_size, void* d_ws, size_t ws_size,
                              hipStream_t stream) {
  const int N = N_NODES;
  const int E = in_sizes[1] / 2;
  const float* x   = (const float*)d_in[0];
  const int*   src = (const int*)d_in[1];
  const int*   dst = src + E;
  const float* Wl1 = (const float*)d_in[2];
  const float* Wr1 = (const float*)d_in[3];
  const float* b1  = (const float*)d_in[4];
  const float* Wl2 = (const float*)d_in[5];
  const float* Wr2 = (const float*)d_in[6];
  const float* b2  = (const float*)d_in[7];
  float* out = (float*)d_out;

  // workspace (~45.3 MB)
  unsigned short* A1 = (unsigned short*)d_ws;         // N*128 bf16
  unsigned short* A2 = A1 + (size_t)N * 128;          // N*256 bf16
  unsigned short* W1 = A2 + (size_t)N * 256;          // 128*128
  unsigned short* W2 = W1 + 128 * 128;                // 128*256
  int* row_start  = (int*)(W2 + 128 * 256);           // N
  int* row_cnt    = row_start + N;                    // N
  int* bucket_cur = row_cnt + N;                      // NBUCK (padded to 392)
  int* buf        = bucket_cur + 392;                 // NBUCK*BCAP ints (6.4 MB)

  prep<<<512, 256, 0, stream>>>(x, Wl1, Wr1, Wl2, Wr2, A1, W1, W2, bucket_cur, N);
  bucket_scatter<<<(E + 4095) / 4096, 1024, 0, stream>>>(src, dst, bucket_cur, buf, E);
  bucket_csr_agg64<<<NBUCK, 1024, 0, stream>>>(buf, bucket_cur, row_start, row_cnt, A1, N);

  int gb = (N + 127) / 128;
  mfma_gemm<128, true><<<gb, 256, 0, stream>>>(A1, W1, b1, A2, nullptr, N, 256, 128);

  int ab = (N * 64 + 255) / 256;  // one wave per node
  agg_mean128<<<ab, 256, 0, stream>>>(A2, row_start, row_cnt, buf, N);
  mfma_gemm<256, false><<<gb, 256, 0, stream>>>(A2, W2, b2, nullptr, out, N, 128, 0);
}

// Round 10
// 200.577 us; speedup vs baseline: 5.8310x; 1.0374x over previous
//
#include <hip/hip_runtime.h>

#define N_NODES 50000
#define NBUCK 391        // ceil(N_NODES / 128) -- 128 dst-nodes per bucket
#define BCAP 4096        // slots per bucket (mean fill 2046, sigma ~45)
#define BSHIFT 12

typedef __attribute__((ext_vector_type(8))) short short8;
typedef __attribute__((ext_vector_type(4))) float floatx4;

static __device__ __forceinline__ unsigned short f2bf(float f) {
  unsigned int u = __builtin_bit_cast(unsigned int, f);
  u += 0x7fff + ((u >> 16) & 1);          // RNE
  return (unsigned short)(u >> 16);
}
static __device__ __forceinline__ float bf2f(unsigned short s) {
  unsigned int u = ((unsigned int)s) << 16;
  return __builtin_bit_cast(float, u);
}

// ---------------- K1: prep (casts) + bucket scatter, fused ----------------
// prep part writes A1 self halves + bf16 weights; scatter part groups edges into
// fixed 4096-slot dst-buckets. The two parts are independent (scatter reads only
// src/dst/bucket_cur; bucket_cur is zeroed by hipMemsetAsync before launch).

__global__ void __launch_bounds__(1024) prep_scatter(
    const float* __restrict__ x,
    const float* __restrict__ Wl1, const float* __restrict__ Wr1,
    const float* __restrict__ Wl2, const float* __restrict__ Wr2,
    unsigned short* __restrict__ A1, unsigned short* __restrict__ W1,
    unsigned short* __restrict__ W2,
    const int* __restrict__ src, const int* __restrict__ dst,
    int* __restrict__ bucket_cur, int* __restrict__ buf, int E, int n) {
  const int t = threadIdx.x;
  const int gid = blockIdx.x * 1024 + t;
  const int gsz = gridDim.x * 1024;
  for (int i = gid; i < n * 64; i += gsz)
    A1[(size_t)(i >> 6) * 128 + 64 + (i & 63)] = f2bf(x[i]);
  for (int i = gid; i < 128 * 128; i += gsz) {
    int c = i >> 7, k = i & 127;
    W1[i] = f2bf(k < 64 ? Wl1[c * 64 + k] : Wr1[c * 64 + k - 64]);
  }
  for (int i = gid; i < 128 * 256; i += gsz) {
    int c = i >> 8, k = i & 255;
    W2[i] = f2bf(k < 128 ? Wl2[c * 128 + k] : Wr2[c * 128 + k - 128]);
  }

  // scatter part: block handles chunk of 4096 edges
  __shared__ int hist[NBUCK];
  __shared__ int base_s[NBUCK];
  for (int i = t; i < NBUCK; i += 1024) hist[i] = 0;
  __syncthreads();
  int e0 = blockIdx.x * 4096;
  int sv[4], dv[4], bv[4];
#pragma unroll
  for (int p = 0; p < 4; ++p) {
    int e = e0 + p * 1024 + t;
    if (e < E) {
      sv[p] = src[e];
      dv[p] = dst[e];
      bv[p] = dv[p] >> 7;
      atomicAdd(&hist[bv[p]], 1);
    } else bv[p] = -1;
  }
  __syncthreads();
  for (int i = t; i < NBUCK; i += 1024) {
    int c = hist[i];
    base_s[i] = c > 0 ? atomicAdd(&bucket_cur[i], c) : 0;
  }
  __syncthreads();
  for (int i = t; i < NBUCK; i += 1024) hist[i] = 0;   // reuse as sub-cursor
  __syncthreads();
#pragma unroll
  for (int p = 0; p < 4; ++p) {
    if (bv[p] >= 0) {
      int sub = base_s[bv[p]] + atomicAdd(&hist[bv[p]], 1);
      if (sub < BCAP) buf[(bv[p] << BSHIFT) + sub] = (sv[p] << 7) | (dv[p] & 127);
    }
  }
}

// ---------------- K2: per-bucket local CSR + fused vectorized layer-1 agg ----------------
// CSR: stage packed edges in LDS, histogram+scan 128 nodes, reorder srcs in place.
// Agg: 16 waves x 8 nodes; lane = (edge-slot eq = lane>>3) x (16B chunk cl = lane&7);
// one dwordx4 load covers 8 edges' 128B rows; 3-hop shfl_xor reduce; lanes eq==0 store.

__global__ void __launch_bounds__(1024) bucket_csr_agg64(
    int* __restrict__ buf, const int* __restrict__ bucket_cur,
    int* __restrict__ row_start, int* __restrict__ row_cnt,
    unsigned short* __restrict__ A1, int n) {
  __shared__ int eb[BCAP];      // 16 KB staged edges
  __shared__ int cnt[128];
  __shared__ int tmp[128];
  __shared__ int cur[128];
  const int t = threadIdx.x;
  const int b = blockIdx.x;
  const int node0 = b << 7;
  const int len = min(bucket_cur[b], BCAP);
  int* reg = buf + (b << BSHIFT);
  if (t < 128) cnt[t] = 0;
  __syncthreads();
  for (int i = t; i < len; i += 1024) {
    int p = reg[i];
    eb[i] = p;
    atomicAdd(&cnt[p & 127], 1);
  }
  __syncthreads();
  if (t < 128) tmp[t] = cnt[t];
  __syncthreads();
#pragma unroll
  for (int off = 1; off < 128; off <<= 1) {
    int u = (t >= off && t < 128) ? tmp[t - off] : 0;
    __syncthreads();
    if (t < 128) tmp[t] += u;
    __syncthreads();
  }
  if (t < 128) {
    int ex = tmp[t] - cnt[t];          // exclusive local prefix
    cur[t] = ex;
    int nd = node0 + t;
    if (nd < n) {
      row_start[nd] = (b << BSHIFT) + ex;
      row_cnt[nd] = cnt[t];
    }
  }
  __syncthreads();
  for (int i = t; i < len; i += 1024) {
    int p = eb[i];
    int sub = atomicAdd(&cur[p & 127], 1);
    reg[sub] = p >> 7;                 // in-place: packed -> plain src, grouped by node
  }
  __syncthreads();
  // fused vectorized agg64
  const int lane = t & 63;
  const int wv = t >> 6;
  const int eq = lane >> 3;            // edge slot 0..7
  const int cl = lane & 7;             // 16B chunk: cols cl*8..cl*8+7
  for (int loc = wv; loc < 128; loc += 16) {
    int nd = node0 + loc;
    if (nd >= n) break;                // monotonic in loc
    int cn = cnt[loc];
    const int* sp = reg + (tmp[loc] - cn);
    float acc[8];
#pragma unroll
    for (int j = 0; j < 8; ++j) acc[j] = 0.f;
    for (int e = 0; e < cn; e += 8) {
      if (e + eq < cn) {
        int s = sp[e + eq];
        short8 v = *(const short8*)(A1 + (size_t)s * 128 + 64 + cl * 8);
#pragma unroll
        for (int j = 0; j < 8; ++j) acc[j] += bf2f((unsigned short)v[j]);
      }
    }
#pragma unroll
    for (int j = 0; j < 8; ++j) {
      acc[j] += __shfl_xor(acc[j], 8, 64);
      acc[j] += __shfl_xor(acc[j], 16, 64);
      acc[j] += __shfl_xor(acc[j], 32, 64);
    }
    if (eq == 0) {
      float inv = 1.0f / (float)max(cn, 1);
      short8 o;
#pragma unroll
      for (int j = 0; j < 8; ++j) o[j] = (short)f2bf(acc[j] * inv);
      *(short8*)(A1 + (size_t)nd * 128 + cl * 8) = o;
    }
  }
}

// ---------------- K4: layer-2 aggregation (wave per node, vectorized) ----------------
// lane = (edge-slot eq = lane>>4) x (16B chunk cl = lane&15); one dwordx4 load
// covers 4 edges' 256B rows; 2-hop shfl_xor reduce; lanes eq==0 store 16B each.

__global__ void agg_mean128(unsigned short* __restrict__ A2,
    const int* __restrict__ row_start, const int* __restrict__ row_cnt,
    const int* __restrict__ srcs, int n) {
  int wid = (blockIdx.x * blockDim.x + threadIdx.x) >> 6;
  int lane = threadIdx.x & 63;
  if (wid >= n) return;
  int start = row_start[wid];
  int cnt = row_cnt[wid];
  const int eq = lane >> 4;            // edge slot 0..3
  const int cl = lane & 15;            // 16B chunk: cols cl*8..cl*8+7
  float acc[8];
#pragma unroll
  for (int j = 0; j < 8; ++j) acc[j] = 0.f;
  for (int e = 0; e < cnt; e += 4) {
    if (e + eq < cnt) {
      int s = srcs[start + e + eq];
      short8 v = *(const short8*)(A2 + (size_t)s * 256 + 128 + cl * 8);
#pragma unroll
      for (int j = 0; j < 8; ++j) acc[j] += bf2f((unsigned short)v[j]);
    }
  }
#pragma unroll
  for (int j = 0; j < 8; ++j) {
    acc[j] += __shfl_xor(acc[j], 16, 64);
    acc[j] += __shfl_xor(acc[j], 32, 64);
  }
  if (eq == 0) {
    float inv = 1.0f / (float)max(cnt, 1);
    short8 o;
#pragma unroll
    for (int j = 0; j < 8; ++j) o[j] = (short)f2bf(acc[j] * inv);
    *(short8*)(A2 + (size_t)wid * 256 + cl * 8) = o;
  }
}

// ---------------- K3/K5: MFMA GEMM: out = relu(A'(n,KP) x W'(128,KP)^T + bias) ----------------

template<int KP, bool BF_OUT>
__global__ void __launch_bounds__(256) mfma_gemm(
    const unsigned short* __restrict__ A, const unsigned short* __restrict__ W,
    const float* __restrict__ bias, unsigned short* __restrict__ outb,
    float* __restrict__ outf, int n, int ostride, int ocol) {
  const int lane = threadIdx.x & 63;
  const int wv = threadIdx.x >> 6;
  const int m = lane & 15;
  const int q = lane >> 4;
  const int r0 = blockIdx.x * 128 + wv * 32;

  floatx4 acc[2][8];
#pragma unroll
  for (int rt = 0; rt < 2; ++rt)
#pragma unroll
    for (int ct = 0; ct < 8; ++ct) acc[rt][ct] = (floatx4){0.f, 0.f, 0.f, 0.f};

  int ra = r0 + m;      if (ra > n - 1) ra = n - 1;
  int rb = r0 + 16 + m; if (rb > n - 1) rb = n - 1;
  const unsigned short* Arow0 = A + (size_t)ra * KP + q * 8;
  const unsigned short* Arow1 = A + (size_t)rb * KP + q * 8;
  const unsigned short* Wrow  = W + (size_t)m * KP + q * 8;

#pragma unroll 1
  for (int kc = 0; kc < KP / 32; ++kc) {
    short8 a0 = *(const short8*)(Arow0 + kc * 32);
    short8 a1 = *(const short8*)(Arow1 + kc * 32);
#pragma unroll
    for (int ct = 0; ct < 8; ++ct) {
      short8 wf = *(const short8*)(Wrow + (size_t)ct * 16 * KP + kc * 32);
      acc[0][ct] = __builtin_amdgcn_mfma_f32_16x16x32_bf16(a0, wf, acc[0][ct], 0, 0, 0);
      acc[1][ct] = __builtin_amdgcn_mfma_f32_16x16x32_bf16(a1, wf, acc[1][ct], 0, 0, 0);
    }
  }

  float bv[8];
#pragma unroll
  for (int ct = 0; ct < 8; ++ct) bv[ct] = bias[ct * 16 + m];

#pragma unroll
  for (int rt = 0; rt < 2; ++rt) {
#pragma unroll
    for (int j = 0; j < 4; ++j) {
      int row = r0 + rt * 16 + q * 4 + j;
      if (row < n) {
#pragma unroll
        for (int ct = 0; ct < 8; ++ct) {
          float v = acc[rt][ct][j] + bv[ct];
          v = v > 0.f ? v : 0.f;
          int col = ct * 16 + m;
          if (BF_OUT) outb[(size_t)row * ostride + ocol + col] = f2bf(v);
          else        outf[(size_t)row * ostride + col] = v;
        }
      }
    }
  }
}

// ---------------- launch ----------------

extern "C" void kernel_launch(void* const* d_in, const int* in_sizes, int n_in,
                              void* d_out, int out_size, void* d_ws, size_t ws_size,
                              hipStream_t stream) {
  const int N = N_NODES;
  const int E = in_sizes[1] / 2;
  const float* x   = (const float*)d_in[0];
  const int*   src = (const int*)d_in[1];
  const int*   dst = src + E;
  const float* Wl1 = (const float*)d_in[2];
  const float* Wr1 = (const float*)d_in[3];
  const float* b1  = (const float*)d_in[4];
  const float* Wl2 = (const float*)d_in[5];
  const float* Wr2 = (const float*)d_in[6];
  const float* b2  = (const float*)d_in[7];
  float* out = (float*)d_out;

  // workspace (~45.3 MB)
  unsigned short* A1 = (unsigned short*)d_ws;         // N*128 bf16
  unsigned short* A2 = A1 + (size_t)N * 128;          // N*256 bf16
  unsigned short* W1 = A2 + (size_t)N * 256;          // 128*128
  unsigned short* W2 = W1 + 128 * 128;                // 128*256
  int* row_start  = (int*)(W2 + 128 * 256);           // N
  int* row_cnt    = row_start + N;                    // N
  int* bucket_cur = row_cnt + N;                      // NBUCK (padded to 392)
  int* buf        = bucket_cur + 392;                 // NBUCK*BCAP ints (6.4 MB)

  hipMemsetAsync(bucket_cur, 0, NBUCK * sizeof(int), stream);
  int sb = (E + 4095) / 4096;                         // 196 blocks
  prep_scatter<<<sb, 1024, 0, stream>>>(x, Wl1, Wr1, Wl2, Wr2, A1, W1, W2,
                                        src, dst, bucket_cur, buf, E, N);
  bucket_csr_agg64<<<NBUCK, 1024, 0, stream>>>(buf, bucket_cur, row_start, row_cnt, A1, N);

  int gb = (N + 127) / 128;
  mfma_gemm<128, true><<<gb, 256, 0, stream>>>(A1, W1, b1, A2, nullptr, N, 256, 128);

  int ab = (N * 64 + 255) / 256;  // one wave per node
  agg_mean128<<<ab, 256, 0, stream>>>(A2, row_start, row_cnt, buf, N);
  mfma_gemm<256, false><<<gb, 256, 0, stream>>>(A2, W2, b2, nullptr, out, N, 128, 0);
}

// Round 11
// 193.773 us; speedup vs baseline: 6.0357x; 1.0351x over previous
//
#include <hip/hip_runtime.h>

#define N_NODES 50000
#define NBUCK 391        // ceil(N_NODES / 128) -- 128 dst-nodes per bucket = one GEMM tile
#define BCAP 4096        // slots per bucket (mean fill 2046, sigma ~45)
#define BSHIFT 12

typedef __attribute__((ext_vector_type(8))) short short8;
typedef __attribute__((ext_vector_type(4))) float floatx4;

static __device__ __forceinline__ unsigned short f2bf(float f) {
  unsigned int u = __builtin_bit_cast(unsigned int, f);
  u += 0x7fff + ((u >> 16) & 1);          // RNE
  return (unsigned short)(u >> 16);
}
static __device__ __forceinline__ float bf2f(unsigned short s) {
  unsigned int u = ((unsigned int)s) << 16;
  return __builtin_bit_cast(float, u);
}

// ---------------- K1: prep (casts) + bucket scatter, fused ----------------

__global__ void __launch_bounds__(1024) prep_scatter(
    const float* __restrict__ x,
    const float* __restrict__ Wl1, const float* __restrict__ Wr1,
    const float* __restrict__ Wl2, const float* __restrict__ Wr2,
    unsigned short* __restrict__ xb, unsigned short* __restrict__ W1,
    unsigned short* __restrict__ W2,
    const int* __restrict__ src, const int* __restrict__ dst,
    int* __restrict__ bucket_cur, int* __restrict__ buf, int E, int n) {
  const int t = threadIdx.x;
  const int gid = blockIdx.x * 1024 + t;
  const int gsz = gridDim.x * 1024;
  for (int i = gid; i < n * 64; i += gsz) xb[i] = f2bf(x[i]);
  for (int i = gid; i < 128 * 128; i += gsz) {
    int c = i >> 7, k = i & 127;
    W1[i] = f2bf(k < 64 ? Wl1[c * 64 + k] : Wr1[c * 64 + k - 64]);
  }
  for (int i = gid; i < 128 * 256; i += gsz) {
    int c = i >> 8, k = i & 255;
    W2[i] = f2bf(k < 128 ? Wl2[c * 128 + k] : Wr2[c * 128 + k - 128]);
  }

  // scatter: block handles chunk of 4096 edges; packed = (src<<7)|(dst&127)
  __shared__ int hist[NBUCK];
  __shared__ int base_s[NBUCK];
  for (int i = t; i < NBUCK; i += 1024) hist[i] = 0;
  __syncthreads();
  int e0 = blockIdx.x * 4096;
  int sv[4], dv[4], bv[4];
#pragma unroll
  for (int p = 0; p < 4; ++p) {
    int e = e0 + p * 1024 + t;
    if (e < E) {
      sv[p] = src[e];
      dv[p] = dst[e];
      bv[p] = dv[p] >> 7;
      atomicAdd(&hist[bv[p]], 1);
    } else bv[p] = -1;
  }
  __syncthreads();
  for (int i = t; i < NBUCK; i += 1024) {
    int c = hist[i];
    base_s[i] = c > 0 ? atomicAdd(&bucket_cur[i], c) : 0;
  }
  __syncthreads();
  for (int i = t; i < NBUCK; i += 1024) hist[i] = 0;   // reuse as sub-cursor
  __syncthreads();
#pragma unroll
  for (int p = 0; p < 4; ++p) {
    if (bv[p] >= 0) {
      int sub = base_s[bv[p]] + atomicAdd(&hist[bv[p]], 1);
      if (sub < BCAP) buf[(bv[p] << BSHIFT) + sub] = (sv[p] << 7) | (dv[p] & 127);
    }
  }
}

// ---------------- K2: bucket CSR + agg64 (LDS tile) + layer-1 MFMA GEMM ----------------
// One 1024-thread block per bucket (= 128 dst nodes = one GEMM row tile).
// h1[r][c] = relu( sum_k agg64[r][k]*W1[c][k] + xb[r][k]*W1[c][64+k] + b1[c] )

__global__ void __launch_bounds__(1024) csr_agg_gemm1(
    int* __restrict__ buf, const int* __restrict__ bucket_cur,
    int* __restrict__ row_start, int* __restrict__ row_cnt,
    const unsigned short* __restrict__ xb, const unsigned short* __restrict__ W1,
    const float* __restrict__ b1, unsigned short* __restrict__ h1, int n) {
  __shared__ int eb[BCAP];                             // 16 KB staged edges
  __shared__ __align__(16) unsigned short aggS[128 * 72];  // 18 KB agg tile (pad 64->72)
  __shared__ int cnt[128];
  __shared__ int tmp[128];
  __shared__ int cur[128];
  const int t = threadIdx.x;
  const int b = blockIdx.x;
  const int node0 = b << 7;
  const int len = min(bucket_cur[b], BCAP);
  int* reg = buf + (b << BSHIFT);

  // --- CSR build ---
  if (t < 128) cnt[t] = 0;
  __syncthreads();
  for (int i = t; i < len; i += 1024) {
    int p = reg[i];
    eb[i] = p;
    atomicAdd(&cnt[p & 127], 1);
  }
  __syncthreads();
  if (t < 128) tmp[t] = cnt[t];
  __syncthreads();
#pragma unroll
  for (int off = 1; off < 128; off <<= 1) {
    int u = (t >= off && t < 128) ? tmp[t - off] : 0;
    __syncthreads();
    if (t < 128) tmp[t] += u;
    __syncthreads();
  }
  if (t < 128) {
    int ex = tmp[t] - cnt[t];
    cur[t] = ex;
    int nd = node0 + t;
    if (nd < n) {
      row_start[nd] = (b << BSHIFT) + ex;
      row_cnt[nd] = cnt[t];
    }
  }
  __syncthreads();
  for (int i = t; i < len; i += 1024) {
    int p = eb[i];
    int sub = atomicAdd(&cur[p & 127], 1);
    reg[sub] = p >> 7;                 // in-place: grouped src lists (kept for K3)
  }
  __syncthreads();

  // --- vectorized agg64 into LDS: 16 waves x 8 nodes; 8 edge-slots x 8-col chunks ---
  const int lane = t & 63;
  const int wv = t >> 6;
  const int eq = lane >> 3;            // edge slot 0..7
  const int cl = lane & 7;             // 16B chunk: cols cl*8..cl*8+7
  for (int loc = wv; loc < 128; loc += 16) {
    int nd = node0 + loc;
    int cn = (nd < n) ? cnt[loc] : 0;
    const int* sp = reg + (tmp[loc] - cnt[loc]);
    float ac[8], ac2[8];
#pragma unroll
    for (int j = 0; j < 8; ++j) { ac[j] = 0.f; ac2[j] = 0.f; }
    int e = 0;
    for (; e + 16 <= cn; e += 16) {    // two independent 8-edge gathers in flight
      int s0 = sp[e + eq];
      int s1 = sp[e + 8 + eq];
      short8 v0 = *(const short8*)(xb + (size_t)s0 * 64 + cl * 8);
      short8 v1 = *(const short8*)(xb + (size_t)s1 * 64 + cl * 8);
#pragma unroll
      for (int j = 0; j < 8; ++j) { ac[j] += bf2f((unsigned short)v0[j]); ac2[j] += bf2f((unsigned short)v1[j]); }
    }
    for (; e < cn; e += 8) {
      if (e + eq < cn) {
        int s = sp[e + eq];
        short8 v = *(const short8*)(xb + (size_t)s * 64 + cl * 8);
#pragma unroll
        for (int j = 0; j < 8; ++j) ac[j] += bf2f((unsigned short)v[j]);
      }
    }
#pragma unroll
    for (int j = 0; j < 8; ++j) {
      ac[j] += ac2[j];
      ac[j] += __shfl_xor(ac[j], 8, 64);
      ac[j] += __shfl_xor(ac[j], 16, 64);
      ac[j] += __shfl_xor(ac[j], 32, 64);
    }
    if (eq == 0) {
      float inv = 1.0f / (float)max(cn, 1);
      short8 o;
#pragma unroll
      for (int j = 0; j < 8; ++j) o[j] = (short)f2bf(ac[j] * inv);
      *(short8*)(aggS + loc * 72 + cl * 8) = o;   // zeros for invalid nodes (cn=0)
    }
  }
  __syncthreads();

  // --- MFMA gemm1: wave = 32 rows x 32 cols; K=128 (agg LDS | self global) ---
  const int m = lane & 15;
  const int q = lane >> 4;
  const int rw = (wv & 3) * 32;
  const int cw = (wv >> 2) * 32;
  floatx4 acc[2][2];
#pragma unroll
  for (int rt = 0; rt < 2; ++rt)
#pragma unroll
    for (int ct = 0; ct < 2; ++ct) acc[rt][ct] = (floatx4){0.f, 0.f, 0.f, 0.f};

  int ra = node0 + rw + m;      if (ra > n - 1) ra = n - 1;
  int rb = node0 + rw + 16 + m; if (rb > n - 1) rb = n - 1;
  const unsigned short* selfA0 = xb + (size_t)ra * 64 + q * 8;
  const unsigned short* selfA1 = xb + (size_t)rb * 64 + q * 8;
  const unsigned short* aggL0 = aggS + (rw + m) * 72 + q * 8;
  const unsigned short* aggL1 = aggS + (rw + 16 + m) * 72 + q * 8;
  const unsigned short* Wc0 = W1 + (size_t)(cw + m) * 128 + q * 8;
  const unsigned short* Wc1 = W1 + (size_t)(cw + 16 + m) * 128 + q * 8;

#pragma unroll
  for (int kc = 0; kc < 2; ++kc) {     // agg half: k 0..63
    short8 a0 = *(const short8*)(aggL0 + kc * 32);
    short8 a1 = *(const short8*)(aggL1 + kc * 32);
    short8 w0 = *(const short8*)(Wc0 + kc * 32);
    short8 w1 = *(const short8*)(Wc1 + kc * 32);
    acc[0][0] = __builtin_amdgcn_mfma_f32_16x16x32_bf16(a0, w0, acc[0][0], 0, 0, 0);
    acc[0][1] = __builtin_amdgcn_mfma_f32_16x16x32_bf16(a0, w1, acc[0][1], 0, 0, 0);
    acc[1][0] = __builtin_amdgcn_mfma_f32_16x16x32_bf16(a1, w0, acc[1][0], 0, 0, 0);
    acc[1][1] = __builtin_amdgcn_mfma_f32_16x16x32_bf16(a1, w1, acc[1][1], 0, 0, 0);
  }
#pragma unroll
  for (int kc = 0; kc < 2; ++kc) {     // self half: k 64..127
    short8 a0 = *(const short8*)(selfA0 + kc * 32);
    short8 a1 = *(const short8*)(selfA1 + kc * 32);
    short8 w0 = *(const short8*)(Wc0 + 64 + kc * 32);
    short8 w1 = *(const short8*)(Wc1 + 64 + kc * 32);
    acc[0][0] = __builtin_amdgcn_mfma_f32_16x16x32_bf16(a0, w0, acc[0][0], 0, 0, 0);
    acc[0][1] = __builtin_amdgcn_mfma_f32_16x16x32_bf16(a0, w1, acc[0][1], 0, 0, 0);
    acc[1][0] = __builtin_amdgcn_mfma_f32_16x16x32_bf16(a1, w0, acc[1][0], 0, 0, 0);
    acc[1][1] = __builtin_amdgcn_mfma_f32_16x16x32_bf16(a1, w1, acc[1][1], 0, 0, 0);
  }

  float bv0 = b1[cw + m], bv1 = b1[cw + 16 + m];
#pragma unroll
  for (int rt = 0; rt < 2; ++rt) {
#pragma unroll
    for (int j = 0; j < 4; ++j) {
      int row = node0 + rw + rt * 16 + q * 4 + j;
      if (row < n) {
        float v0 = acc[rt][0][j] + bv0; v0 = v0 > 0.f ? v0 : 0.f;
        float v1 = acc[rt][1][j] + bv1; v1 = v1 > 0.f ? v1 : 0.f;
        h1[(size_t)row * 128 + cw + m] = f2bf(v0);
        h1[(size_t)row * 128 + cw + 16 + m] = f2bf(v1);
      }
    }
  }
}

// ---------------- K3: agg128 (LDS tile) + layer-2 MFMA GEMM ----------------
// out[r][c] = relu( sum_k agg128[r][k]*W2[c][k] + h1[r][k]*W2[c][128+k] + b2[c] )

__global__ void __launch_bounds__(1024) agg_gemm2(
    const unsigned short* __restrict__ h1, const int* __restrict__ row_start,
    const int* __restrict__ row_cnt, const int* __restrict__ buf,
    const unsigned short* __restrict__ W2, const float* __restrict__ b2,
    float* __restrict__ out, int n) {
  __shared__ __align__(16) unsigned short aggS[128 * 136];  // 34 KB (pad 128->136)
  const int t = threadIdx.x;
  const int lane = t & 63;
  const int wv = t >> 6;
  const int node0 = blockIdx.x << 7;

  // --- vectorized agg128: 16 waves x 8 nodes; 4 edge-slots x 16-col chunks ---
  const int eq = lane >> 4;            // edge slot 0..3
  const int cl = lane & 15;            // 16B chunk: cols cl*8..cl*8+7
  for (int loc = wv; loc < 128; loc += 16) {
    int nd = node0 + loc;
    int cn = 0, start = 0;
    if (nd < n) { cn = row_cnt[nd]; start = row_start[nd]; }
    float ac[8], ac2[8];
#pragma unroll
    for (int j = 0; j < 8; ++j) { ac[j] = 0.f; ac2[j] = 0.f; }
    int e = 0;
    for (; e + 8 <= cn; e += 8) {      // two independent 4-edge gathers in flight
      int s0 = buf[start + e + eq];
      int s1 = buf[start + e + 4 + eq];
      short8 v0 = *(const short8*)(h1 + (size_t)s0 * 128 + cl * 8);
      short8 v1 = *(const short8*)(h1 + (size_t)s1 * 128 + cl * 8);
#pragma unroll
      for (int j = 0; j < 8; ++j) { ac[j] += bf2f((unsigned short)v0[j]); ac2[j] += bf2f((unsigned short)v1[j]); }
    }
    for (; e < cn; e += 4) {
      if (e + eq < cn) {
        int s = buf[start + e + eq];
        short8 v = *(const short8*)(h1 + (size_t)s * 128 + cl * 8);
#pragma unroll
        for (int j = 0; j < 8; ++j) ac[j] += bf2f((unsigned short)v[j]);
      }
    }
#pragma unroll
    for (int j = 0; j < 8; ++j) {
      ac[j] += ac2[j];
      ac[j] += __shfl_xor(ac[j], 16, 64);
      ac[j] += __shfl_xor(ac[j], 32, 64);
    }
    if (eq == 0) {
      float inv = 1.0f / (float)max(cn, 1);
      short8 o;
#pragma unroll
      for (int j = 0; j < 8; ++j) o[j] = (short)f2bf(ac[j] * inv);
      *(short8*)(aggS + loc * 136 + cl * 8) = o;
    }
  }
  __syncthreads();

  // --- MFMA gemm2: wave = 32 rows x 32 cols; K=256 (agg LDS | self global) ---
  const int m = lane & 15;
  const int q = lane >> 4;
  const int rw = (wv & 3) * 32;
  const int cw = (wv >> 2) * 32;
  floatx4 acc[2][2];
#pragma unroll
  for (int rt = 0; rt < 2; ++rt)
#pragma unroll
    for (int ct = 0; ct < 2; ++ct) acc[rt][ct] = (floatx4){0.f, 0.f, 0.f, 0.f};

  int ra = node0 + rw + m;      if (ra > n - 1) ra = n - 1;
  int rb = node0 + rw + 16 + m; if (rb > n - 1) rb = n - 1;
  const unsigned short* selfA0 = h1 + (size_t)ra * 128 + q * 8;
  const unsigned short* selfA1 = h1 + (size_t)rb * 128 + q * 8;
  const unsigned short* aggL0 = aggS + (rw + m) * 136 + q * 8;
  const unsigned short* aggL1 = aggS + (rw + 16 + m) * 136 + q * 8;
  const unsigned short* Wc0 = W2 + (size_t)(cw + m) * 256 + q * 8;
  const unsigned short* Wc1 = W2 + (size_t)(cw + 16 + m) * 256 + q * 8;

#pragma unroll
  for (int kc = 0; kc < 4; ++kc) {     // agg half: k 0..127
    short8 a0 = *(const short8*)(aggL0 + kc * 32);
    short8 a1 = *(const short8*)(aggL1 + kc * 32);
    short8 w0 = *(const short8*)(Wc0 + kc * 32);
    short8 w1 = *(const short8*)(Wc1 + kc * 32);
    acc[0][0] = __builtin_amdgcn_mfma_f32_16x16x32_bf16(a0, w0, acc[0][0], 0, 0, 0);
    acc[0][1] = __builtin_amdgcn_mfma_f32_16x16x32_bf16(a0, w1, acc[0][1], 0, 0, 0);
    acc[1][0] = __builtin_amdgcn_mfma_f32_16x16x32_bf16(a1, w0, acc[1][0], 0, 0, 0);
    acc[1][1] = __builtin_amdgcn_mfma_f32_16x16x32_bf16(a1, w1, acc[1][1], 0, 0, 0);
  }
#pragma unroll
  for (int kc = 0; kc < 4; ++kc) {     // self half: k 128..255
    short8 a0 = *(const short8*)(selfA0 + kc * 32);
    short8 a1 = *(const short8*)(selfA1 + kc * 32);
    short8 w0 = *(const short8*)(Wc0 + 128 + kc * 32);
    short8 w1 = *(const short8*)(Wc1 + 128 + kc * 32);
    acc[0][0] = __builtin_amdgcn_mfma_f32_16x16x32_bf16(a0, w0, acc[0][0], 0, 0, 0);
    acc[0][1] = __builtin_amdgcn_mfma_f32_16x16x32_bf16(a0, w1, acc[0][1], 0, 0, 0);
    acc[1][0] = __builtin_amdgcn_mfma_f32_16x16x32_bf16(a1, w0, acc[1][0], 0, 0, 0);
    acc[1][1] = __builtin_amdgcn_mfma_f32_16x16x32_bf16(a1, w1, acc[1][1], 0, 0, 0);
  }

  float bv0 = b2[cw + m], bv1 = b2[cw + 16 + m];
#pragma unroll
  for (int rt = 0; rt < 2; ++rt) {
#pragma unroll
    for (int j = 0; j < 4; ++j) {
      int row = node0 + rw + rt * 16 + q * 4 + j;
      if (row < n) {
        float v0 = acc[rt][0][j] + bv0; v0 = v0 > 0.f ? v0 : 0.f;
        float v1 = acc[rt][1][j] + bv1; v1 = v1 > 0.f ? v1 : 0.f;
        out[(size_t)row * 128 + cw + m] = v0;
        out[(size_t)row * 128 + cw + 16 + m] = v1;
      }
    }
  }
}

// ---------------- launch ----------------

extern "C" void kernel_launch(void* const* d_in, const int* in_sizes, int n_in,
                              void* d_out, int out_size, void* d_ws, size_t ws_size,
                              hipStream_t stream) {
  const int N = N_NODES;
  const int E = in_sizes[1] / 2;
  const float* x   = (const float*)d_in[0];
  const int*   src = (const int*)d_in[1];
  const int*   dst = src + E;
  const float* Wl1 = (const float*)d_in[2];
  const float* Wr1 = (const float*)d_in[3];
  const float* b1  = (const float*)d_in[4];
  const float* Wl2 = (const float*)d_in[5];
  const float* Wr2 = (const float*)d_in[6];
  const float* b2  = (const float*)d_in[7];
  float* out = (float*)d_out;

  // workspace (~26 MB)
  unsigned short* xb = (unsigned short*)d_ws;         // N*64 bf16 (x cast)
  unsigned short* h1 = xb + (size_t)N * 64;           // N*128 bf16 (layer-1 out)
  unsigned short* W1 = h1 + (size_t)N * 128;          // 128*128
  unsigned short* W2 = W1 + 128 * 128;                // 128*256
  int* row_start  = (int*)(W2 + 128 * 256);           // N
  int* row_cnt    = row_start + N;                    // N
  int* bucket_cur = row_cnt + N;                      // NBUCK (padded to 392)
  int* buf        = bucket_cur + 392;                 // NBUCK*BCAP ints (6.4 MB)

  hipMemsetAsync(bucket_cur, 0, NBUCK * sizeof(int), stream);
  int sb = (E + 4095) / 4096;                         // 196 blocks
  prep_scatter<<<sb, 1024, 0, stream>>>(x, Wl1, Wr1, Wl2, Wr2, xb, W1, W2,
                                        src, dst, bucket_cur, buf, E, N);
  csr_agg_gemm1<<<NBUCK, 1024, 0, stream>>>(buf, bucket_cur, row_start, row_cnt,
                                            xb, W1, b1, h1, N);
  agg_gemm2<<<NBUCK, 1024, 0, stream>>>(h1, row_start, row_cnt, buf, W2, b2, out, N);
}